// Round 9
// baseline (901.993 us; speedup 1.0000x reference)
//
#include <hip/hip_runtime.h>
#include <math.h>

#define NPG 500      // nodes per graph
#define DIM 256      // feature dim
#define HID 64       // hidden dim
#define RATIO_NORM 600.0f

// ---------------------------------------------------------------- K1: scores
// score[n] = relu(x[n,:] @ Ws1 + bs1) @ Ws2 + bs2
// LDS-broadcast-BW model (r6/r8 fit): wave64 b128 broadcast read costs ~12cy
// of LDS return path. Fix = more nodes per weight read. 8 waves = 8 h-slices
// of 8; M=8 nodes/lane -> 512 nodes/block, grid 196 (1 block/CU).
// Per CU per k4: LDS 8w*8r*12=768cy < VALU 8w*512cy/4=1024cy -> VALU-bound.
__global__ __launch_bounds__(512, 2) void k_score(
    const float* __restrict__ x,
    const float* __restrict__ Ws1,   // [DIM][HID] row-major
    const float* __restrict__ bs1,   // [HID]
    const float* __restrict__ Ws2,   // [HID]
    const float* __restrict__ bs2,   // [1]
    float* __restrict__ score, int N)
{
    __shared__ float w_lds[DIM * HID];   // 64 KB (reused as part[] later)

    int tid = threadIdx.x;
    // cooperative stage of Ws1 (proven replay-stable pattern from r6/r8)
    {
        const float4* src = reinterpret_cast<const float4*>(Ws1);
        float4* dst = reinterpret_cast<float4*>(w_lds);
        for (int i = tid; i < DIM * HID / 4; i += 512) dst[i] = src[i];
    }
    __syncthreads();

    int lane = tid & 63;
    int wv   = tid >> 6;        // 0..7 = h-slice id
    int h0   = wv * 8;
    int nbase = blockIdx.x * 512;

    const float4* xr[8];
#pragma unroll
    for (int m = 0; m < 8; ++m) {
        int n = nbase + m * 64 + lane;
        int nc = n < N ? n : (N - 1);
        xr[m] = reinterpret_cast<const float4*>(x + (size_t)nc * DIM);
    }

    const float* bs = bs1 + h0;
    float4 bA = *reinterpret_cast<const float4*>(bs);
    float4 bB = *reinterpret_cast<const float4*>(bs + 4);
    float4 accA[8], accB[8];
#pragma unroll
    for (int m = 0; m < 8; ++m) { accA[m] = bA; accB[m] = bB; }

    // 2-deep x prefetch: 8 independent streams per lane
    float4 xc[8], xn[8];
#pragma unroll
    for (int m = 0; m < 8; ++m) { xc[m] = xr[m][0]; xn[m] = xr[m][1]; }

    for (int k4 = 0; k4 < DIM / 4; ++k4) {
        const float* wb = w_lds + (size_t)(k4 * 4) * HID + h0;
#pragma unroll
        for (int kk = 0; kk < 4; ++kk) {
            float4 w0 = *reinterpret_cast<const float4*>(wb + kk * HID);
            float4 w1 = *reinterpret_cast<const float4*>(wb + kk * HID + 4);
#pragma unroll
            for (int m = 0; m < 8; ++m) {
                float xk = kk == 0 ? xc[m].x : kk == 1 ? xc[m].y
                         : kk == 2 ? xc[m].z : xc[m].w;
                accA[m].x = fmaf(xk, w0.x, accA[m].x);
                accA[m].y = fmaf(xk, w0.y, accA[m].y);
                accA[m].z = fmaf(xk, w0.z, accA[m].z);
                accA[m].w = fmaf(xk, w0.w, accA[m].w);
                accB[m].x = fmaf(xk, w1.x, accB[m].x);
                accB[m].y = fmaf(xk, w1.y, accB[m].y);
                accB[m].z = fmaf(xk, w1.z, accB[m].z);
                accB[m].w = fmaf(xk, w1.w, accB[m].w);
            }
        }
        int ix = k4 + 2 < DIM / 4 ? k4 + 2 : DIM / 4 - 1;
#pragma unroll
        for (int m = 0; m < 8; ++m) { xc[m] = xn[m]; xn[m] = xr[m][ix]; }
    }

    // second layer partial on this wave's 8 h
    float4 w20 = *reinterpret_cast<const float4*>(Ws2 + h0);
    float4 w21 = *reinterpret_cast<const float4*>(Ws2 + h0 + 4);
    float p[8];
#pragma unroll
    for (int m = 0; m < 8; ++m) {
        float v = 0.0f;
        v = fmaf(fmaxf(accA[m].x, 0.0f), w20.x, v);
        v = fmaf(fmaxf(accA[m].y, 0.0f), w20.y, v);
        v = fmaf(fmaxf(accA[m].z, 0.0f), w20.z, v);
        v = fmaf(fmaxf(accA[m].w, 0.0f), w20.w, v);
        v = fmaf(fmaxf(accB[m].x, 0.0f), w21.x, v);
        v = fmaf(fmaxf(accB[m].y, 0.0f), w21.y, v);
        v = fmaf(fmaxf(accB[m].z, 0.0f), w21.z, v);
        v = fmaf(fmaxf(accB[m].w, 0.0f), w21.w, v);
        p[m] = v;
    }

    // reduce across 8 h-slices; reuse w_lds as part[8][512]
    __syncthreads();                       // all waves done reading weights
#pragma unroll
    for (int m = 0; m < 8; ++m)
        w_lds[wv * 512 + m * 64 + lane] = p[m];
    __syncthreads();
    {
        float s = bs2[0];
#pragma unroll
        for (int j = 0; j < 8; ++j) s += w_lds[j * 512 + tid];
        int node = nbase + tid;
        if (node < N) score[node] = s;
    }
}

// ------------------------------------------------------------- K2: edge count
__global__ __launch_bounds__(256) void k_edges(
    const int* __restrict__ esrc, const int* __restrict__ edst,
    int* __restrict__ counts, int E, int G)
{
    __shared__ int hist[256];
    for (int i = threadIdx.x; i < G; i += 256) hist[i] = 0;
    __syncthreads();

    int nchunk = E >> 2;
    const int4* s4 = reinterpret_cast<const int4*>(esrc);
    const int4* d4 = reinterpret_cast<const int4*>(edst);
    for (int c = blockIdx.x * 256 + threadIdx.x; c < nchunk; c += gridDim.x * 256) {
        int4 s = s4[c], d = d4[c];
        int g;
        g = s.x / NPG; if (g == d.x / NPG) atomicAdd(&hist[g], 1);
        g = s.y / NPG; if (g == d.y / NPG) atomicAdd(&hist[g], 1);
        g = s.z / NPG; if (g == d.z / NPG) atomicAdd(&hist[g], 1);
        g = s.w / NPG; if (g == d.w / NPG) atomicAdd(&hist[g], 1);
    }
    if (blockIdx.x == 0) {
        for (int e = (nchunk << 2) + threadIdx.x; e < E; e += 256) {
            int g = esrc[e] / NPG;
            if (g == edst[e] / NPG) atomicAdd(&hist[g], 1);
        }
    }
    __syncthreads();
    for (int i = threadIdx.x; i < G; i += 256)
        if (hist[i]) atomicAdd(&counts[i], hist[i]);
}

// ------------------------------------------- K3: per-graph avg + keep_num MLP
__global__ __launch_bounds__(256) void k_keep(
    const float* __restrict__ score,
    const int* __restrict__ counts,
    const float* __restrict__ Wp1,   // [3][HID]
    const float* __restrict__ bp1,   // [HID]
    const float* __restrict__ Wp2,   // [HID]
    const float* __restrict__ bp2,   // [1]
    int* __restrict__ keep_num)
{
    int g = blockIdx.x;
    __shared__ float red[256];
    const float* s = score + (size_t)g * NPG;
    float v = 0.0f;
    for (int i = threadIdx.x; i < NPG; i += 256) v += s[i];
    red[threadIdx.x] = v;
    __syncthreads();
    for (int off = 128; off >= 1; off >>= 1) {
        if (threadIdx.x < off) red[threadIdx.x] += red[threadIdx.x + off];
        __syncthreads();
    }
    if (threadIdx.x < 64) {
        float f0 = (float)NPG / RATIO_NORM;
        float f1 = red[0] / (float)NPG;
        float f2 = (float)counts[g] / (float)(NPG * (NPG - 1));
        int h = threadIdx.x;
        float hv = bp1[h];
        hv = fmaf(f0, Wp1[h], hv);
        hv = fmaf(f1, Wp1[HID + h], hv);
        hv = fmaf(f2, Wp1[2 * HID + h], hv);
        hv = fmaxf(hv, 0.0f) * Wp2[h];
#pragma unroll
        for (int m = 32; m >= 1; m >>= 1) hv += __shfl_xor(hv, m, 64);
        if (h == 0) {
            float z = hv + bp2[0];
            float kr = 1.0f / (1.0f + expf(-z));
            int kn = (int)((float)NPG * kr);
            keep_num[g] = kn < 2 ? 2 : kn;
        }
    }
}

// ---------------------------- K4a: per-graph rank -> mask (float) + gate tanh
__global__ __launch_bounds__(256) void k_rank(
    const float* __restrict__ score,
    const int* __restrict__ keep_num,
    float* __restrict__ out_mask,   // [N] 0.0/1.0
    float* __restrict__ gate)       // [N] tanh(score) or 0
{
    int g = blockIdx.x;
    __shared__ float s[NPG];
    const float* sg = score + (size_t)g * NPG;
    for (int i = threadIdx.x; i < NPG; i += 256) s[i] = sg[i];
    __syncthreads();

    int kn = keep_num[g];
    for (int i = threadIdx.x; i < NPG; i += 256) {
        float si = s[i];
        int rank = 0;
        for (int j = 0; j < NPG; ++j) {
            float sj = s[j];
            rank += (sj > si) || ((sj == si) && (j < i));
        }
        bool keep = rank < kn;
        size_t idx = (size_t)g * NPG + i;
        out_mask[idx] = keep ? 1.0f : 0.0f;
        gate[idx] = keep ? tanhf(si) : 0.0f;
    }
}

// ------------------------------------------ K4b: gated row write (full BW)
__global__ __launch_bounds__(256) void k_write(
    const float* __restrict__ x,
    const float* __restrict__ gate,
    float* __restrict__ out_x, int N)
{
    int lane = threadIdx.x & 63;
    int row = blockIdx.x * 4 + (threadIdx.x >> 6);
    if (row >= N) return;
    float gt = gate[row];
    size_t base = (size_t)row * DIM;
    float4* o = reinterpret_cast<float4*>(out_x + base);
    if (gt != 0.0f) {
        const float4* xi = reinterpret_cast<const float4*>(x + base);
        float4 v = xi[lane];
        o[lane] = make_float4(v.x * gt, v.y * gt, v.z * gt, v.w * gt);
    } else {
        o[lane] = make_float4(0.0f, 0.0f, 0.0f, 0.0f);
    }
}

// ---------------------------------------------------------------------- host
extern "C" void kernel_launch(void* const* d_in, const int* in_sizes, int n_in,
                              void* d_out, int out_size, void* d_ws, size_t ws_size,
                              hipStream_t stream)
{
    const float* x   = (const float*)d_in[0];
    const float* Ws1 = (const float*)d_in[1];
    const float* bs1 = (const float*)d_in[2];
    const float* Ws2 = (const float*)d_in[3];
    const float* bs2 = (const float*)d_in[4];
    const float* Wp1 = (const float*)d_in[5];
    const float* bp1 = (const float*)d_in[6];
    const float* Wp2 = (const float*)d_in[7];
    const float* bp2 = (const float*)d_in[8];
    const int* esrc  = (const int*)d_in[9];
    const int* edst  = (const int*)d_in[10];

    int E = in_sizes[9];
    int N = in_sizes[0] / DIM;
    int G = N / NPG;

    float* score = (float*)d_ws;                               // N floats
    float* gate  = score + N;                                  // N floats
    int* counts  = (int*)(gate + N);                           // G ints
    int* keep    = counts + G;                                 // G ints

    float* out_x    = (float*)d_out;
    float* out_mask = out_x + (size_t)N * DIM;

    hipMemsetAsync(counts, 0, G * sizeof(int), stream);
    k_score<<<(N + 511) / 512, 512, 0, stream>>>(x, Ws1, bs1, Ws2, bs2, score, N);
    k_edges<<<512, 256, 0, stream>>>(esrc, edst, counts, E, G);
    k_keep<<<G, 256, 0, stream>>>(score, counts, Wp1, bp1, Wp2, bp2, keep);
    k_rank<<<G, 256, 0, stream>>>(score, keep, out_mask, gate);
    k_write<<<(N + 3) / 4, 256, 0, stream>>>(x, gate, out_x, N);
}

// Round 10
// 207.939 us; speedup vs baseline: 4.3378x; 4.3378x over previous
//
#include <hip/hip_runtime.h>
#include <math.h>

#define NPG 500      // nodes per graph
#define DIM 256      // feature dim
#define HID 64       // hidden dim
#define RATIO_NORM 600.0f

// ---------------------------------------------------------------- K1: scores
// score[n] = relu(x[n,:] @ Ws1 + bs1) @ Ws2 + bs2
// LDS-broadcast model: LDS:VALU = 12:2M -> M=4 gives ~65% VALU duty without
// the register blowup that sank M=8 (r9 spilled: WRITE_SIZE 570MB).
// 8 waves = 8 h-slices of 8, M=4 nodes/lane -> 256 nodes/block, grid 391,
// 64KB LDS, 2 blocks/CU residency, 4 waves/SIMD.
__global__ __launch_bounds__(512, 4) void k_score(
    const float* __restrict__ x,
    const float* __restrict__ Ws1,   // [DIM][HID] row-major
    const float* __restrict__ bs1,   // [HID]
    const float* __restrict__ Ws2,   // [HID]
    const float* __restrict__ bs2,   // [1]
    float* __restrict__ score, int N)
{
    __shared__ float w_lds[DIM * HID];   // 64 KB (reused as part[] later)

    int tid = threadIdx.x;
    // cooperative stage of Ws1 (replay-stable pattern from r6/r8)
    {
        const float4* src = reinterpret_cast<const float4*>(Ws1);
        float4* dst = reinterpret_cast<float4*>(w_lds);
        for (int i = tid; i < DIM * HID / 4; i += 512) dst[i] = src[i];
    }
    __syncthreads();

    int lane = tid & 63;
    int wv   = tid >> 6;        // 0..7 = h-slice id
    int h0   = wv * 8;
    int nbase = blockIdx.x * 256;

    const float4* xr0; const float4* xr1; const float4* xr2; const float4* xr3;
    {
        int n0 = nbase + lane;            n0 = n0 < N ? n0 : (N - 1);
        int n1 = nbase + 64 + lane;       n1 = n1 < N ? n1 : (N - 1);
        int n2 = nbase + 128 + lane;      n2 = n2 < N ? n2 : (N - 1);
        int n3 = nbase + 192 + lane;      n3 = n3 < N ? n3 : (N - 1);
        xr0 = reinterpret_cast<const float4*>(x + (size_t)n0 * DIM);
        xr1 = reinterpret_cast<const float4*>(x + (size_t)n1 * DIM);
        xr2 = reinterpret_cast<const float4*>(x + (size_t)n2 * DIM);
        xr3 = reinterpret_cast<const float4*>(x + (size_t)n3 * DIM);
    }

    const float* bs = bs1 + h0;
    float4 bA = *reinterpret_cast<const float4*>(bs);
    float4 bB = *reinterpret_cast<const float4*>(bs + 4);
    float4 aA0 = bA, aB0 = bB;   // node stream 0
    float4 aA1 = bA, aB1 = bB;   // node stream 1
    float4 aA2 = bA, aB2 = bB;   // node stream 2
    float4 aA3 = bA, aB3 = bB;   // node stream 3

    // 1-deep x prefetch, 4 independent streams
    float4 xc0 = xr0[0], xc1 = xr1[0], xc2 = xr2[0], xc3 = xr3[0];
    float4 xn0 = xr0[1], xn1 = xr1[1], xn2 = xr2[1], xn3 = xr3[1];

    for (int k4 = 0; k4 < DIM / 4; ++k4) {
        const float* wb = w_lds + (size_t)(k4 * 4) * HID + h0;
#pragma unroll
        for (int kk = 0; kk < 4; ++kk) {
            float4 w0 = *reinterpret_cast<const float4*>(wb + kk * HID);
            float4 w1 = *reinterpret_cast<const float4*>(wb + kk * HID + 4);
            float xk0 = kk == 0 ? xc0.x : kk == 1 ? xc0.y : kk == 2 ? xc0.z : xc0.w;
            float xk1 = kk == 0 ? xc1.x : kk == 1 ? xc1.y : kk == 2 ? xc1.z : xc1.w;
            float xk2 = kk == 0 ? xc2.x : kk == 1 ? xc2.y : kk == 2 ? xc2.z : xc2.w;
            float xk3 = kk == 0 ? xc3.x : kk == 1 ? xc3.y : kk == 2 ? xc3.z : xc3.w;
            aA0.x = fmaf(xk0, w0.x, aA0.x);  aB0.x = fmaf(xk0, w1.x, aB0.x);
            aA0.y = fmaf(xk0, w0.y, aA0.y);  aB0.y = fmaf(xk0, w1.y, aB0.y);
            aA0.z = fmaf(xk0, w0.z, aA0.z);  aB0.z = fmaf(xk0, w1.z, aB0.z);
            aA0.w = fmaf(xk0, w0.w, aA0.w);  aB0.w = fmaf(xk0, w1.w, aB0.w);
            aA1.x = fmaf(xk1, w0.x, aA1.x);  aB1.x = fmaf(xk1, w1.x, aB1.x);
            aA1.y = fmaf(xk1, w0.y, aA1.y);  aB1.y = fmaf(xk1, w1.y, aB1.y);
            aA1.z = fmaf(xk1, w0.z, aA1.z);  aB1.z = fmaf(xk1, w1.z, aB1.z);
            aA1.w = fmaf(xk1, w0.w, aA1.w);  aB1.w = fmaf(xk1, w1.w, aB1.w);
            aA2.x = fmaf(xk2, w0.x, aA2.x);  aB2.x = fmaf(xk2, w1.x, aB2.x);
            aA2.y = fmaf(xk2, w0.y, aA2.y);  aB2.y = fmaf(xk2, w1.y, aB2.y);
            aA2.z = fmaf(xk2, w0.z, aA2.z);  aB2.z = fmaf(xk2, w1.z, aB2.z);
            aA2.w = fmaf(xk2, w0.w, aA2.w);  aB2.w = fmaf(xk2, w1.w, aB2.w);
            aA3.x = fmaf(xk3, w0.x, aA3.x);  aB3.x = fmaf(xk3, w1.x, aB3.x);
            aA3.y = fmaf(xk3, w0.y, aA3.y);  aB3.y = fmaf(xk3, w1.y, aB3.y);
            aA3.z = fmaf(xk3, w0.z, aA3.z);  aB3.z = fmaf(xk3, w1.z, aB3.z);
            aA3.w = fmaf(xk3, w0.w, aA3.w);  aB3.w = fmaf(xk3, w1.w, aB3.w);
        }
        int ix = k4 + 2 < DIM / 4 ? k4 + 2 : DIM / 4 - 1;
        xc0 = xn0; xn0 = xr0[ix];
        xc1 = xn1; xn1 = xr1[ix];
        xc2 = xn2; xn2 = xr2[ix];
        xc3 = xn3; xn3 = xr3[ix];
    }

    // second layer partial on this wave's 8 h
    float4 w20 = *reinterpret_cast<const float4*>(Ws2 + h0);
    float4 w21 = *reinterpret_cast<const float4*>(Ws2 + h0 + 4);
    float p0 = 0.0f, p1 = 0.0f, p2 = 0.0f, p3 = 0.0f;
    p0 = fmaf(fmaxf(aA0.x, 0.0f), w20.x, p0);
    p0 = fmaf(fmaxf(aA0.y, 0.0f), w20.y, p0);
    p0 = fmaf(fmaxf(aA0.z, 0.0f), w20.z, p0);
    p0 = fmaf(fmaxf(aA0.w, 0.0f), w20.w, p0);
    p0 = fmaf(fmaxf(aB0.x, 0.0f), w21.x, p0);
    p0 = fmaf(fmaxf(aB0.y, 0.0f), w21.y, p0);
    p0 = fmaf(fmaxf(aB0.z, 0.0f), w21.z, p0);
    p0 = fmaf(fmaxf(aB0.w, 0.0f), w21.w, p0);
    p1 = fmaf(fmaxf(aA1.x, 0.0f), w20.x, p1);
    p1 = fmaf(fmaxf(aA1.y, 0.0f), w20.y, p1);
    p1 = fmaf(fmaxf(aA1.z, 0.0f), w20.z, p1);
    p1 = fmaf(fmaxf(aA1.w, 0.0f), w20.w, p1);
    p1 = fmaf(fmaxf(aB1.x, 0.0f), w21.x, p1);
    p1 = fmaf(fmaxf(aB1.y, 0.0f), w21.y, p1);
    p1 = fmaf(fmaxf(aB1.z, 0.0f), w21.z, p1);
    p1 = fmaf(fmaxf(aB1.w, 0.0f), w21.w, p1);
    p2 = fmaf(fmaxf(aA2.x, 0.0f), w20.x, p2);
    p2 = fmaf(fmaxf(aA2.y, 0.0f), w20.y, p2);
    p2 = fmaf(fmaxf(aA2.z, 0.0f), w20.z, p2);
    p2 = fmaf(fmaxf(aA2.w, 0.0f), w20.w, p2);
    p2 = fmaf(fmaxf(aB2.x, 0.0f), w21.x, p2);
    p2 = fmaf(fmaxf(aB2.y, 0.0f), w21.y, p2);
    p2 = fmaf(fmaxf(aB2.z, 0.0f), w21.z, p2);
    p2 = fmaf(fmaxf(aB2.w, 0.0f), w21.w, p2);
    p3 = fmaf(fmaxf(aA3.x, 0.0f), w20.x, p3);
    p3 = fmaf(fmaxf(aA3.y, 0.0f), w20.y, p3);
    p3 = fmaf(fmaxf(aA3.z, 0.0f), w20.z, p3);
    p3 = fmaf(fmaxf(aA3.w, 0.0f), w20.w, p3);
    p3 = fmaf(fmaxf(aB3.x, 0.0f), w21.x, p3);
    p3 = fmaf(fmaxf(aB3.y, 0.0f), w21.y, p3);
    p3 = fmaf(fmaxf(aB3.z, 0.0f), w21.z, p3);
    p3 = fmaf(fmaxf(aB3.w, 0.0f), w21.w, p3);

    // reduce across 8 h-slices; reuse w_lds as part[8][256]
    __syncthreads();                       // all waves done reading weights
    w_lds[wv * 256 + lane]       = p0;
    w_lds[wv * 256 + 64 + lane]  = p1;
    w_lds[wv * 256 + 128 + lane] = p2;
    w_lds[wv * 256 + 192 + lane] = p3;
    __syncthreads();
    if (tid < 256) {
        float s = bs2[0];
#pragma unroll
        for (int j = 0; j < 8; ++j) s += w_lds[j * 256 + tid];
        int node = nbase + tid;
        if (node < N) score[node] = s;
    }
}

// ------------------------------------------------------------- K2: edge count
__global__ __launch_bounds__(256) void k_edges(
    const int* __restrict__ esrc, const int* __restrict__ edst,
    int* __restrict__ counts, int E, int G)
{
    __shared__ int hist[256];
    for (int i = threadIdx.x; i < G; i += 256) hist[i] = 0;
    __syncthreads();

    int nchunk = E >> 2;
    const int4* s4 = reinterpret_cast<const int4*>(esrc);
    const int4* d4 = reinterpret_cast<const int4*>(edst);
    for (int c = blockIdx.x * 256 + threadIdx.x; c < nchunk; c += gridDim.x * 256) {
        int4 s = s4[c], d = d4[c];
        int g;
        g = s.x / NPG; if (g == d.x / NPG) atomicAdd(&hist[g], 1);
        g = s.y / NPG; if (g == d.y / NPG) atomicAdd(&hist[g], 1);
        g = s.z / NPG; if (g == d.z / NPG) atomicAdd(&hist[g], 1);
        g = s.w / NPG; if (g == d.w / NPG) atomicAdd(&hist[g], 1);
    }
    if (blockIdx.x == 0) {
        for (int e = (nchunk << 2) + threadIdx.x; e < E; e += 256) {
            int g = esrc[e] / NPG;
            if (g == edst[e] / NPG) atomicAdd(&hist[g], 1);
        }
    }
    __syncthreads();
    for (int i = threadIdx.x; i < G; i += 256)
        if (hist[i]) atomicAdd(&counts[i], hist[i]);
}

// ------------------------------------------- K3: per-graph avg + keep_num MLP
__global__ __launch_bounds__(256) void k_keep(
    const float* __restrict__ score,
    const int* __restrict__ counts,
    const float* __restrict__ Wp1,   // [3][HID]
    const float* __restrict__ bp1,   // [HID]
    const float* __restrict__ Wp2,   // [HID]
    const float* __restrict__ bp2,   // [1]
    int* __restrict__ keep_num)
{
    int g = blockIdx.x;
    __shared__ float red[256];
    const float* s = score + (size_t)g * NPG;
    float v = 0.0f;
    for (int i = threadIdx.x; i < NPG; i += 256) v += s[i];
    red[threadIdx.x] = v;
    __syncthreads();
    for (int off = 128; off >= 1; off >>= 1) {
        if (threadIdx.x < off) red[threadIdx.x] += red[threadIdx.x + off];
        __syncthreads();
    }
    if (threadIdx.x < 64) {
        float f0 = (float)NPG / RATIO_NORM;
        float f1 = red[0] / (float)NPG;
        float f2 = (float)counts[g] / (float)(NPG * (NPG - 1));
        int h = threadIdx.x;
        float hv = bp1[h];
        hv = fmaf(f0, Wp1[h], hv);
        hv = fmaf(f1, Wp1[HID + h], hv);
        hv = fmaf(f2, Wp1[2 * HID + h], hv);
        hv = fmaxf(hv, 0.0f) * Wp2[h];
#pragma unroll
        for (int m = 32; m >= 1; m >>= 1) hv += __shfl_xor(hv, m, 64);
        if (h == 0) {
            float z = hv + bp2[0];
            float kr = 1.0f / (1.0f + expf(-z));
            int kn = (int)((float)NPG * kr);
            keep_num[g] = kn < 2 ? 2 : kn;
        }
    }
}

// ---------------------------- K4a: per-graph rank -> mask (float) + gate tanh
__global__ __launch_bounds__(256) void k_rank(
    const float* __restrict__ score,
    const int* __restrict__ keep_num,
    float* __restrict__ out_mask,   // [N] 0.0/1.0
    float* __restrict__ gate)       // [N] tanh(score) or 0
{
    int g = blockIdx.x;
    __shared__ float s[NPG];
    const float* sg = score + (size_t)g * NPG;
    for (int i = threadIdx.x; i < NPG; i += 256) s[i] = sg[i];
    __syncthreads();

    int kn = keep_num[g];
    for (int i = threadIdx.x; i < NPG; i += 256) {
        float si = s[i];
        int rank = 0;
        for (int j = 0; j < NPG; ++j) {
            float sj = s[j];
            rank += (sj > si) || ((sj == si) && (j < i));
        }
        bool keep = rank < kn;
        size_t idx = (size_t)g * NPG + i;
        out_mask[idx] = keep ? 1.0f : 0.0f;
        gate[idx] = keep ? tanhf(si) : 0.0f;
    }
}

// ------------------------------------------ K4b: gated row write (full BW)
__global__ __launch_bounds__(256) void k_write(
    const float* __restrict__ x,
    const float* __restrict__ gate,
    float* __restrict__ out_x, int N)
{
    int lane = threadIdx.x & 63;
    int row = blockIdx.x * 4 + (threadIdx.x >> 6);
    if (row >= N) return;
    float gt = gate[row];
    size_t base = (size_t)row * DIM;
    float4* o = reinterpret_cast<float4*>(out_x + base);
    if (gt != 0.0f) {
        const float4* xi = reinterpret_cast<const float4*>(x + base);
        float4 v = xi[lane];
        o[lane] = make_float4(v.x * gt, v.y * gt, v.z * gt, v.w * gt);
    } else {
        o[lane] = make_float4(0.0f, 0.0f, 0.0f, 0.0f);
    }
}

// ---------------------------------------------------------------------- host
extern "C" void kernel_launch(void* const* d_in, const int* in_sizes, int n_in,
                              void* d_out, int out_size, void* d_ws, size_t ws_size,
                              hipStream_t stream)
{
    const float* x   = (const float*)d_in[0];
    const float* Ws1 = (const float*)d_in[1];
    const float* bs1 = (const float*)d_in[2];
    const float* Ws2 = (const float*)d_in[3];
    const float* bs2 = (const float*)d_in[4];
    const float* Wp1 = (const float*)d_in[5];
    const float* bp1 = (const float*)d_in[6];
    const float* Wp2 = (const float*)d_in[7];
    const float* bp2 = (const float*)d_in[8];
    const int* esrc  = (const int*)d_in[9];
    const int* edst  = (const int*)d_in[10];

    int E = in_sizes[9];
    int N = in_sizes[0] / DIM;
    int G = N / NPG;

    float* score = (float*)d_ws;                               // N floats
    float* gate  = score + N;                                  // N floats
    int* counts  = (int*)(gate + N);                           // G ints
    int* keep    = counts + G;                                 // G ints

    float* out_x    = (float*)d_out;
    float* out_mask = out_x + (size_t)N * DIM;

    hipMemsetAsync(counts, 0, G * sizeof(int), stream);
    k_score<<<(N + 255) / 256, 512, 0, stream>>>(x, Ws1, bs1, Ws2, bs2, score, N);
    k_edges<<<512, 256, 0, stream>>>(esrc, edst, counts, E, G);
    k_keep<<<G, 256, 0, stream>>>(score, counts, Wp1, bp1, Wp2, bp2, keep);
    k_rank<<<G, 256, 0, stream>>>(score, keep, out_mask, gate);
    k_write<<<(N + 3) / 4, 256, 0, stream>>>(x, gate, out_x, N);
}